// Round 1
// baseline (1479.095 us; speedup 1.0000x reference)
//
#include <hip/hip_runtime.h>
#include <math.h>

// SigmaMoE: x[4,2048,1024] f32, expert_sel[16,1024], keys[16,1024,256],
// values[16,256,1024], route_scale[1] -> out[4,2048,1024] f32.
// Strategy: fp32 routing + top-4 (exact vs ref), expert-grouped fp32 FFN,
// atomicAdd f32 epilogue (4 writers per output element).

constexpr int NTOK = 8192;   // 4*2048
constexpr int DM   = 1024;
constexpr int NE   = 16;
constexpr int EH   = 256;
constexpr int TK   = 4;
constexpr int CAP  = 8192;   // max tokens per expert (each token once per expert)
constexpr int TM   = 64;     // token tile in ffn kernel
constexpr int KC   = 32;     // k-chunk

// ---------------- K1: routing ----------------
// 256 threads = 16 tokens/block; each 16-lane group handles one token
// (lane%16 = expert). fp32 logits -> sigmoid -> top-4 (min-index tiebreak,
// matching jax.lax.top_k stability) -> normalized weights -> scatter to
// per-expert lists via atomicAdd on counts.
__global__ __launch_bounds__(256) void route_kernel(
    const float* __restrict__ x, const float* __restrict__ esel,
    const float* __restrict__ rscale,
    int* __restrict__ counts, int* __restrict__ ltok, float* __restrict__ lw)
{
    int tid = threadIdx.x;
    int e_lane = tid & 15;
    int t = blockIdx.x * 16 + (tid >> 4);

    const float4* x4 = (const float4*)(x + (size_t)t * DM);
    const float4* s4 = (const float4*)(esel + (size_t)e_lane * DM);
    float acc = 0.f;
    #pragma unroll 8
    for (int i = 0; i < DM / 4; ++i) {
        float4 a = x4[i], b = s4[i];
        acc += a.x * b.x + a.y * b.y + a.z * b.z + a.w * b.w;
    }
    float p = 1.0f / (1.0f + expf(-acc));

    float myv = p;
    float sum = 0.f;
    int   sel_e[TK];
    float sel_p[TK];
    #pragma unroll
    for (int k = 0; k < TK; ++k) {
        float v = myv; int ie = e_lane;
        #pragma unroll
        for (int off = 8; off; off >>= 1) {
            float ov = __shfl_xor(v, off, 16);
            int   oe = __shfl_xor(ie, off, 16);
            if (ov > v || (ov == v && oe < ie)) { v = ov; ie = oe; }
        }
        sel_e[k] = ie; sel_p[k] = v; sum += v;
        if (e_lane == ie) myv = -INFINITY;   // remove from next rounds
    }

    if (e_lane == 0) {
        float w_scale = rscale[0] / fmaxf(sum, 1e-9f);
        #pragma unroll
        for (int k = 0; k < TK; ++k) {
            int e = sel_e[k];
            int slot = atomicAdd(&counts[e], 1);
            ltok[e * CAP + slot] = t;
            lw[e * CAP + slot]   = sel_p[k] * w_scale;
        }
    }
}

// ---------------- K2: expert-grouped FFN ----------------
// grid = (CAP/TM, NE); block = 512 threads (8 waves).
// Per block: expert e, up to 64 tokens.
//  Phase 1: H[64][256] = relu(X[64][1024] @ keys[e])   (k-loop over DM)
//  Phase 2: out[64][1024] += w * (H @ values[e])       (4 n-chunks of 256)
// Thread tile 4 tokens x 8 cols; LDS: XsT 8KB + Ks/Vs 32KB + HsT 64KB.
__global__ __launch_bounds__(512) void ffn_kernel(
    const float* __restrict__ x, const float* __restrict__ keys,
    const float* __restrict__ values,
    const int* __restrict__ counts, const int* __restrict__ ltok,
    const float* __restrict__ lw, float* __restrict__ out)
{
    int e   = blockIdx.y;
    int cnt = counts[e];
    int t0  = blockIdx.x * TM;
    if (t0 >= cnt) return;

    __shared__ float XsT[KC][TM];   // x chunk, transposed [d][t]
    __shared__ float Ks[KC][EH];    // keys / values chunk [d][j]
    __shared__ float HsT[EH][TM];   // hidden, transposed [h][t]
    __shared__ int   stok[TM];
    __shared__ float sw[TM];

    int tid = threadIdx.x;
    if (tid < TM) {
        int s = t0 + tid;
        if (s < cnt) { stok[tid] = ltok[e * CAP + s]; sw[tid] = lw[e * CAP + s]; }
        else         { stok[tid] = 0;                 sw[tid] = 0.f; }
    }
    __syncthreads();

    int rg = tid >> 5;   // 0..15 -> token rows rg*4..+3
    int cg = tid & 31;   // 0..31 -> cols cg*8..+7

    float acc[4][8];
    #pragma unroll
    for (int i = 0; i < 4; ++i)
        #pragma unroll
        for (int j = 0; j < 8; ++j) acc[i][j] = 0.f;

    // ---- Phase 1: H = relu(X @ K_e) ----
    for (int kc = 0; kc < DM; kc += KC) {
        {   // stage XsT: 64 tok x 32 d (one float4 per thread), transposed
            int s = tid >> 3;          // token slot 0..63
            int q = tid & 7;           // d-offset q*4
            float4 v = *(const float4*)(x + (size_t)stok[s] * DM + kc + q * 4);
            XsT[q * 4 + 0][s] = v.x; XsT[q * 4 + 1][s] = v.y;
            XsT[q * 4 + 2][s] = v.z; XsT[q * 4 + 3][s] = v.w;
        }
        {   // stage Ks: 32 x 256 contiguous block of keys[e]
            const float4* src = (const float4*)(keys + ((size_t)e * DM + kc) * EH);
            float4* dst = (float4*)(&Ks[0][0]);
            #pragma unroll
            for (int r = 0; r < 4; ++r) dst[tid + r * 512] = src[tid + r * 512];
        }
        __syncthreads();
        #pragma unroll 8
        for (int d = 0; d < KC; ++d) {
            float xa[4], kb[8];
            #pragma unroll
            for (int i = 0; i < 4; ++i) xa[i] = XsT[d][rg * 4 + i];
            #pragma unroll
            for (int j = 0; j < 8; ++j) kb[j] = Ks[d][cg * 8 + j];
            #pragma unroll
            for (int i = 0; i < 4; ++i)
                #pragma unroll
                for (int j = 0; j < 8; ++j)
                    acc[i][j] = fmaf(xa[i], kb[j], acc[i][j]);
        }
        __syncthreads();
    }

    // relu -> HsT
    #pragma unroll
    for (int i = 0; i < 4; ++i)
        #pragma unroll
        for (int j = 0; j < 8; ++j)
            HsT[cg * 8 + j][rg * 4 + i] = fmaxf(acc[i][j], 0.f);
    __syncthreads();

    // ---- Phase 2: out += w * (H @ V_e), 4 col-chunks of 256 ----
    for (int nb = 0; nb < 4; ++nb) {
        int n0 = nb * 256;
        float acc2[4][8];
        #pragma unroll
        for (int i = 0; i < 4; ++i)
            #pragma unroll
            for (int j = 0; j < 8; ++j) acc2[i][j] = 0.f;

        for (int hc = 0; hc < EH; hc += KC) {
            {   // stage Vs (reuse Ks buffer): 32 rows x 256 cols, row stride DM
                int r  = tid >> 4;     // 0..31
                int c4 = tid & 15;     // float4 col base
                const float4* vsrc =
                    (const float4*)(values + ((size_t)e * EH + hc + r) * DM + n0);
                float4* vdst = (float4*)(&Ks[r][0]);
                #pragma unroll
                for (int q = 0; q < 4; ++q) vdst[c4 + q * 16] = vsrc[c4 + q * 16];
            }
            __syncthreads();
            #pragma unroll 8
            for (int d = 0; d < KC; ++d) {
                float ha[4], vb[8];
                #pragma unroll
                for (int i = 0; i < 4; ++i) ha[i] = HsT[hc + d][rg * 4 + i];
                #pragma unroll
                for (int j = 0; j < 8; ++j) vb[j] = Ks[d][cg * 8 + j];
                #pragma unroll
                for (int i = 0; i < 4; ++i)
                    #pragma unroll
                    for (int j = 0; j < 8; ++j)
                        acc2[i][j] = fmaf(ha[i], vb[j], acc2[i][j]);
            }
            __syncthreads();
        }

        #pragma unroll
        for (int i = 0; i < 4; ++i) {
            int   t = stok[rg * 4 + i];
            float w = sw[rg * 4 + i];
            float* op = out + (size_t)t * DM + n0 + cg * 8;
            #pragma unroll
            for (int j = 0; j < 8; ++j) atomicAdd(&op[j], w * acc2[i][j]);
        }
    }
}

extern "C" void kernel_launch(void* const* d_in, const int* in_sizes, int n_in,
                              void* d_out, int out_size, void* d_ws, size_t ws_size,
                              hipStream_t stream) {
    const float* x      = (const float*)d_in[0];
    const float* esel   = (const float*)d_in[1];
    const float* keys   = (const float*)d_in[2];
    const float* values = (const float*)d_in[3];
    const float* rscale = (const float*)d_in[4];
    float* out = (float*)d_out;

    char* ws   = (char*)d_ws;
    int*  counts = (int*)ws;                                   // 16 ints
    int*  ltok   = (int*)(ws + 256);                           // [16][8192]
    float* lw    = (float*)(ws + 256 + (size_t)NE * CAP * 4);  // [16][8192]

    hipMemsetAsync(counts, 0, 256, stream);
    hipMemsetAsync(d_out, 0, (size_t)out_size * sizeof(float), stream);

    route_kernel<<<NTOK / 16, 256, 0, stream>>>(x, esel, rscale, counts, ltok, lw);
    ffn_kernel<<<dim3(CAP / TM, NE), 512, 0, stream>>>(x, keys, values,
                                                       counts, ltok, lw, out);
}

// Round 2
// 281.951 us; speedup vs baseline: 5.2459x; 5.2459x over previous
//
#include <hip/hip_runtime.h>
#include <math.h>

// SigmaMoE bf16-MFMA version.
// x[4,2048,1024] f32, expert_sel[16,1024], keys[16,1024,256],
// values[16,256,1024], route_scale[1] -> out[4,2048,1024] f32.
//
// Pipeline:
//  conv_x:   x f32 -> xb bf16 [8192][1024]
//  trans:    keys  -> keysT  bf16 [16][256][1024]   (B-operand k-contiguous)
//  trans:    values-> valuesT bf16 [16][1024][256]
//  route:    fp32 logits + sigmoid + top-4 (exact) -> per-expert lists (pk=t*4+k)
//  ffn<1>:   per-expert 64-token tiles, MFMA 16x16x32 bf16, XOR-swizzled LDS,
//            global_load_lds staging; writes unweighted bf16 rows to scratch[pk]
//  combine:  out[t] = sum_k wtk[t*4+k] * scratch[t*4+k]   (fp32)
// Fallback ffn<0>: weighted fp32 atomicAdd directly to out (if ws too small).

constexpr int NTOK = 8192;
constexpr int DM   = 1024;
constexpr int NE   = 16;
constexpr int EH   = 256;
constexpr int TK   = 4;
constexpr int CAP  = 8192;
constexpr int TM   = 64;

typedef __attribute__((ext_vector_type(8))) short short8;
typedef __attribute__((ext_vector_type(4))) float f32x4;

#define MFMA16(a, b, c) __builtin_amdgcn_mfma_f32_16x16x32_bf16(a, b, c, 0, 0, 0)

__device__ __forceinline__ void gload_lds16(const void* g, void* l) {
    __builtin_amdgcn_global_load_lds(
        (const __attribute__((address_space(1))) void*)g,
        (__attribute__((address_space(3))) void*)l, 16, 0, 0);
}

__device__ __forceinline__ unsigned short f2bf(float f) {
    union { float f; unsigned int u; } x; x.f = f;
    unsigned int r = x.u + 0x7fffu + ((x.u >> 16) & 1u);  // RNE
    return (unsigned short)(r >> 16);
}
__device__ __forceinline__ float bf2f(unsigned short b) {
    union { unsigned int u; float f; } x; x.u = ((unsigned int)b) << 16;
    return x.f;
}

// ---------------- converts ----------------
__global__ __launch_bounds__(256) void conv_x_kernel(
    const float* __restrict__ x, unsigned short* __restrict__ xb)
{
    size_t i = ((size_t)blockIdx.x * 256 + threadIdx.x) * 8;
    float4 a = *(const float4*)(x + i);
    float4 b = *(const float4*)(x + i + 4);
    ushort4 r0 = { f2bf(a.x), f2bf(a.y), f2bf(a.z), f2bf(a.w) };
    ushort4 r1 = { f2bf(b.x), f2bf(b.y), f2bf(b.z), f2bf(b.w) };
    *(ushort4*)(xb + i) = r0;
    *(ushort4*)(xb + i + 4) = r1;
}

// in [E][R][C] f32 -> out [E][C][R] bf16
__global__ __launch_bounds__(256) void trans_kernel(
    const float* __restrict__ in, unsigned short* __restrict__ outp, int R, int C)
{
    __shared__ float T[32][33];
    int e = blockIdx.z;
    int r0 = blockIdx.y * 32, c0 = blockIdx.x * 32;
    int ri = threadIdx.x >> 3, cq = threadIdx.x & 7;
    float4 v = *(const float4*)(in + ((size_t)e * R + r0 + ri) * C + c0 + cq * 4);
    T[ri][cq * 4 + 0] = v.x; T[ri][cq * 4 + 1] = v.y;
    T[ri][cq * 4 + 2] = v.z; T[ri][cq * 4 + 3] = v.w;
    __syncthreads();
    int ci = threadIdx.x >> 3, rq = threadIdx.x & 7;
    ushort4 o = { f2bf(T[rq * 4 + 0][ci]), f2bf(T[rq * 4 + 1][ci]),
                  f2bf(T[rq * 4 + 2][ci]), f2bf(T[rq * 4 + 3][ci]) };
    *(ushort4*)(outp + ((size_t)e * C + c0 + ci) * R + r0 + rq * 4) = o;
}

// ---------------- routing (fp32, exact top-4) ----------------
__global__ __launch_bounds__(256) void route_kernel(
    const float* __restrict__ x, const float* __restrict__ esel,
    const float* __restrict__ rscale,
    int* __restrict__ counts, int* __restrict__ lpk,
    float* __restrict__ lw, float* __restrict__ wtk)
{
    __shared__ float Xs[64][140];   // pad 140: f4-aligned, bank-spread
    __shared__ float Es[16][140];
    __shared__ float Ls[64][17];
    int tid = threadIdx.x;
    int t0 = blockIdx.x * 64;
    int e = tid & 15, tg = tid >> 4;

    float acc[4] = {0.f, 0.f, 0.f, 0.f};
    for (int kc = 0; kc < DM; kc += 128) {
        #pragma unroll
        for (int it = 0; it < 8; ++it) {
            int idx = tid + it * 256;      // 2048 float4s
            int r = idx >> 5, c4 = idx & 31;
            *(float4*)&Xs[r][c4 * 4] =
                *(const float4*)(x + (size_t)(t0 + r) * DM + kc + c4 * 4);
        }
        #pragma unroll
        for (int it = 0; it < 2; ++it) {
            int idx = tid + it * 256;      // 512 float4s
            int r = idx >> 5, c4 = idx & 31;
            *(float4*)&Es[r][c4 * 4] =
                *(const float4*)(esel + (size_t)r * DM + kc + c4 * 4);
        }
        __syncthreads();
        #pragma unroll 4
        for (int d4 = 0; d4 < 32; ++d4) {
            float4 eb = *(float4*)&Es[e][d4 * 4];
            #pragma unroll
            for (int i = 0; i < 4; ++i) {
                float4 xa = *(float4*)&Xs[tg * 4 + i][d4 * 4];
                acc[i] = fmaf(xa.x, eb.x, acc[i]);
                acc[i] = fmaf(xa.y, eb.y, acc[i]);
                acc[i] = fmaf(xa.z, eb.z, acc[i]);
                acc[i] = fmaf(xa.w, eb.w, acc[i]);
            }
        }
        __syncthreads();
    }
    #pragma unroll
    for (int i = 0; i < 4; ++i) Ls[tg * 4 + i][e] = acc[i];
    __syncthreads();

    float rs = rscale[0];
    for (int ti = 0; ti < 4; ++ti) {
        int trow = ti * 16 + tg;
        float p = 1.0f / (1.0f + expf(-Ls[trow][e]));
        float myv = p, sum = 0.f;
        int sel_e[TK]; float sel_p[TK];
        #pragma unroll
        for (int k = 0; k < TK; ++k) {
            float v = myv; int ie = e;
            #pragma unroll
            for (int off = 8; off; off >>= 1) {
                float ov = __shfl_xor(v, off, 16);
                int   oe = __shfl_xor(ie, off, 16);
                if (ov > v || (ov == v && oe < ie)) { v = ov; ie = oe; }
            }
            sel_e[k] = ie; sel_p[k] = v; sum += v;
            if (e == ie) myv = -INFINITY;
        }
        if (e == 0) {
            int t = t0 + trow;
            float wsc = rs / fmaxf(sum, 1e-9f);
            #pragma unroll
            for (int k = 0; k < TK; ++k) {
                int ex = sel_e[k];
                int slot = atomicAdd(&counts[ex], 1);
                int pk = t * TK + k;
                float wv = sel_p[k] * wsc;
                lpk[ex * CAP + slot] = pk;
                lw[ex * CAP + slot]  = wv;
                wtk[pk] = wv;
            }
        }
    }
}

// ---------------- FFN (MFMA) ----------------
// block: 256 threads (4 waves); per block: expert e, 64 tokens.
// LDS (all bf16, XOR-swizzled byte ^= (row&7)<<4):
//   Xs [64][64]   8KB   x tile
//   KV [256][64] 32KB   keysT / valuesT k-slice
//   Ss [64][256] 32KB   relu scores
template<int USE_SCRATCH>
__global__ __launch_bounds__(256, 2) void ffn_kernel(
    const unsigned short* __restrict__ xb,
    const unsigned short* __restrict__ ktb,   // [16][256][1024]
    const unsigned short* __restrict__ vtb,   // [16][1024][256]
    const int* __restrict__ counts, const int* __restrict__ lpk,
    const float* __restrict__ lw,
    unsigned short* __restrict__ scratch,     // [32769][1024] bf16
    float* __restrict__ out)
{
    int e   = blockIdx.y;
    int cnt = counts[e];
    int t0  = blockIdx.x * TM;
    if (t0 >= cnt) return;

    __shared__ __align__(16) char L[74496];
    char* Xs = L;                // 8KB
    char* KV = L + 8192;         // 32KB
    char* Ss = L + 40960;        // 32KB
    int*   stok = (int*)(L + 73728);
    int*   spk  = (int*)(L + 73984);
    float* sw   = (float*)(L + 74240);

    int tid  = threadIdx.x;
    int lane = tid & 63;
    int w    = tid >> 6;

    if (tid < TM) {
        int s = t0 + tid;
        if (s < cnt) {
            int pk = lpk[e * CAP + s];
            stok[tid] = pk >> 2; spk[tid] = pk; sw[tid] = lw[e * CAP + s];
        } else {
            stok[tid] = 0; spk[tid] = USE_SCRATCH ? (NTOK * TK) : 0; sw[tid] = 0.f;
        }
    }
    __syncthreads();

    f32x4 zero = {0.f, 0.f, 0.f, 0.f};
    f32x4 acc[4][4];
    #pragma unroll
    for (int mi = 0; mi < 4; ++mi)
        #pragma unroll
        for (int ni = 0; ni < 4; ++ni) acc[mi][ni] = zero;

    // ---- phase 1: S = relu(X @ K_e), S[64][256] ----
    for (int kc = 0; kc < DM; kc += 64) {
        #pragma unroll
        for (int c = 0; c < 2; ++c) {          // Xs rows [w*16, +16)
            int base = (w * 16 + c * 8) * 128;
            int P = base + lane * 16;
            int row = P >> 7;
            int A = P ^ ((row & 7) << 4);
            const unsigned short* src =
                xb + (size_t)stok[A >> 7] * DM + kc + ((A & 127) >> 1);
            gload_lds16(src, Xs + base);
        }
        #pragma unroll
        for (int c = 0; c < 8; ++c) {          // KsT rows [w*64, +64)
            int base = (w * 64 + c * 8) * 128;
            int P = base + lane * 16;
            int row = P >> 7;
            int A = P ^ ((row & 7) << 4);
            const unsigned short* src =
                ktb + ((size_t)e * EH + (A >> 7)) * DM + kc + ((A & 127) >> 1);
            gload_lds16(src, KV + base);
        }
        __syncthreads();
        #pragma unroll
        for (int kk = 0; kk < 2; ++kk) {
            short8 a[4], b[4];
            #pragma unroll
            for (int mi = 0; mi < 4; ++mi) {
                int row = mi * 16 + (lane & 15);
                int A = row * 128 + (kk * 32 + (lane >> 4) * 8) * 2;
                a[mi] = *(const short8*)(Xs + (A ^ ((row & 7) << 4)));
            }
            #pragma unroll
            for (int ni = 0; ni < 4; ++ni) {
                int row = w * 64 + ni * 16 + (lane & 15);
                int A = row * 128 + (kk * 32 + (lane >> 4) * 8) * 2;
                b[ni] = *(const short8*)(KV + (A ^ ((row & 7) << 4)));
            }
            #pragma unroll
            for (int mi = 0; mi < 4; ++mi)
                #pragma unroll
                for (int ni = 0; ni < 4; ++ni)
                    acc[mi][ni] = MFMA16(a[mi], b[ni], acc[mi][ni]);
        }
        __syncthreads();
    }

    // relu -> Ss (bf16, swizzled); D layout: col=lane&15, row=(lane>>4)*4+r
    #pragma unroll
    for (int mi = 0; mi < 4; ++mi)
        #pragma unroll
        for (int ni = 0; ni < 4; ++ni) {
            f32x4 v = acc[mi][ni];
            #pragma unroll
            for (int r = 0; r < 4; ++r) {
                int row = mi * 16 + (lane >> 4) * 4 + r;
                int col = w * 64 + ni * 16 + (lane & 15);
                int A = row * 512 + col * 2;
                *(unsigned short*)(Ss + (A ^ ((row & 7) << 4))) =
                    f2bf(fmaxf(v[r], 0.f));
            }
        }
    __syncthreads();

    // ---- phase 2: O = S @ V_e, in 4 n-chunks of 256 ----
    for (int nb = 0; nb < 4; ++nb) {
        f32x4 acc2[4][4];
        #pragma unroll
        for (int mi = 0; mi < 4; ++mi)
            #pragma unroll
            for (int ni = 0; ni < 4; ++ni) acc2[mi][ni] = zero;

        for (int kc = 0; kc < EH; kc += 64) {
            #pragma unroll
            for (int c = 0; c < 8; ++c) {      // VsT rows [w*64, +64)
                int base = (w * 64 + c * 8) * 128;
                int P = base + lane * 16;
                int row = P >> 7;
                int A = P ^ ((row & 7) << 4);
                const unsigned short* src =
                    vtb + ((size_t)e * DM + nb * 256 + (A >> 7)) * EH + kc + ((A & 127) >> 1);
                gload_lds16(src, KV + base);
            }
            __syncthreads();
            #pragma unroll
            for (int kk = 0; kk < 2; ++kk) {
                short8 a[4], b[4];
                #pragma unroll
                for (int mi = 0; mi < 4; ++mi) {
                    int row = mi * 16 + (lane & 15);
                    int A = row * 512 + (kc + kk * 32 + (lane >> 4) * 8) * 2;
                    a[mi] = *(const short8*)(Ss + (A ^ ((row & 7) << 4)));
                }
                #pragma unroll
                for (int ni = 0; ni < 4; ++ni) {
                    int row = w * 64 + ni * 16 + (lane & 15);
                    int A = row * 128 + (kk * 32 + (lane >> 4) * 8) * 2;
                    b[ni] = *(const short8*)(KV + (A ^ ((row & 7) << 4)));
                }
                #pragma unroll
                for (int mi = 0; mi < 4; ++mi)
                    #pragma unroll
                    for (int ni = 0; ni < 4; ++ni)
                        acc2[mi][ni] = MFMA16(a[mi], b[ni], acc2[mi][ni]);
            }
            __syncthreads();
        }

        #pragma unroll
        for (int mi = 0; mi < 4; ++mi)
            #pragma unroll
            for (int ni = 0; ni < 4; ++ni) {
                f32x4 v = acc2[mi][ni];
                #pragma unroll
                for (int r = 0; r < 4; ++r) {
                    int slot = mi * 16 + (lane >> 4) * 4 + r;
                    int d = nb * 256 + w * 64 + ni * 16 + (lane & 15);
                    if (USE_SCRATCH) {
                        scratch[(size_t)spk[slot] * DM + d] = f2bf(v[r]);
                    } else {
                        atomicAdd(out + (size_t)stok[slot] * DM + d, sw[slot] * v[r]);
                    }
                }
            }
    }
}

// ---------------- combine ----------------
__global__ __launch_bounds__(256) void combine_kernel(
    const unsigned short* __restrict__ scratch, const float* __restrict__ wtk,
    float* __restrict__ out)
{
    int t  = blockIdx.x * 2 + (threadIdx.x >> 7);
    int d0 = (threadIdx.x & 127) * 8;
    float o[8] = {0.f, 0.f, 0.f, 0.f, 0.f, 0.f, 0.f, 0.f};
    #pragma unroll
    for (int k = 0; k < TK; ++k) {
        float wv = wtk[t * TK + k];
        uint4 q = *(const uint4*)(scratch + (size_t)(t * TK + k) * DM + d0);
        unsigned int us[4] = {q.x, q.y, q.z, q.w};
        #pragma unroll
        for (int j = 0; j < 4; ++j) {
            o[j * 2 + 0] = fmaf(wv, bf2f((unsigned short)(us[j] & 0xffff)), o[j * 2 + 0]);
            o[j * 2 + 1] = fmaf(wv, bf2f((unsigned short)(us[j] >> 16)),    o[j * 2 + 1]);
        }
    }
    float4 w0 = {o[0], o[1], o[2], o[3]}, w1 = {o[4], o[5], o[6], o[7]};
    *(float4*)(out + (size_t)t * DM + d0)     = w0;
    *(float4*)(out + (size_t)t * DM + d0 + 4) = w1;
}

extern "C" void kernel_launch(void* const* d_in, const int* in_sizes, int n_in,
                              void* d_out, int out_size, void* d_ws, size_t ws_size,
                              hipStream_t stream) {
    const float* x      = (const float*)d_in[0];
    const float* esel   = (const float*)d_in[1];
    const float* keys   = (const float*)d_in[2];
    const float* values = (const float*)d_in[3];
    const float* rscale = (const float*)d_in[4];
    float* out = (float*)d_out;

    char* ws = (char*)d_ws;
    size_t o = 0;
    auto alloc = [&](size_t sz) { size_t r = o; o = (o + sz + 255) & ~(size_t)255; return r; };
    size_t o_counts = alloc(NE * 4);
    size_t o_lpk    = alloc((size_t)NE * CAP * 4);
    size_t o_lw     = alloc((size_t)NE * CAP * 4);
    size_t o_wtk    = alloc((size_t)NTOK * TK * 4);
    size_t o_xb     = alloc((size_t)NTOK * DM * 2);
    size_t o_ktb    = alloc((size_t)NE * EH * DM * 2);
    size_t o_vtb    = alloc((size_t)NE * DM * EH * 2);
    size_t need_small = o;
    size_t o_scr    = alloc(((size_t)NTOK * TK + TM) * DM * 2);
    size_t need_full = o;

    int*            counts  = (int*)(ws + o_counts);
    int*            lpk     = (int*)(ws + o_lpk);
    float*          lw      = (float*)(ws + o_lw);
    float*          wtk     = (float*)(ws + o_wtk);
    unsigned short* xb      = (unsigned short*)(ws + o_xb);
    unsigned short* ktb     = (unsigned short*)(ws + o_ktb);
    unsigned short* vtb     = (unsigned short*)(ws + o_vtb);
    unsigned short* scratch = (unsigned short*)(ws + o_scr);

    bool use_scratch = ws_size >= need_full;
    (void)need_small;

    hipMemsetAsync(counts, 0, 256, stream);
    if (!use_scratch)
        hipMemsetAsync(d_out, 0, (size_t)out_size * sizeof(float), stream);

    conv_x_kernel<<<NTOK * DM / 8 / 256, 256, 0, stream>>>(x, xb);
    trans_kernel<<<dim3(EH / 32, DM / 32, NE), 256, 0, stream>>>(keys, ktb, DM, EH);
    trans_kernel<<<dim3(DM / 32, EH / 32, NE), 256, 0, stream>>>(values, vtb, EH, DM);
    route_kernel<<<NTOK / 64, 256, 0, stream>>>(x, esel, rscale, counts, lpk, lw, wtk);

    if (use_scratch) {
        ffn_kernel<1><<<dim3(CAP / TM, NE), 256, 0, stream>>>(
            xb, ktb, vtb, counts, lpk, lw, scratch, out);
        combine_kernel<<<NTOK / 2, 256, 0, stream>>>(scratch, wtk, out);
    } else {
        ffn_kernel<0><<<dim3(CAP / TM, NE), 256, 0, stream>>>(
            xb, ktb, vtb, counts, lpk, lw, scratch, out);
    }
}